// Round 3
// baseline (607.926 us; speedup 1.0000x reference)
//
#include <hip/hip_runtime.h>

// Round 10: atomicAdd -> unsafeAtomicAdd (native ds_add_f32 probe).
//   R9 post-mortem: bank layout 8-way->2-way INVARIANT (349us), occupancy
//   45->68% INVARIANT (R8), cache path INVARIANT (R5/R6). Fitted cost
//   ~3 cyc per LDS f32 lane-atomic = 10x ds_read throughput (m134) ->
//   suspicion: hipcc lowers atomicAdd(float*) on LDS to a CAS loop
//   (3-4 LDS round trips per add), which is exactly bank/occupancy
//   invariant. unsafeAtomicAdd guarantees native ds_add_f32 /
//   global_atomic_add_f32 lowering (denorm-flush only; tolerance ok).
//   Single-variable change vs R9. If invariant again: HW atomic floor
//   confirmed -> next round = two-level sort + register accumulation.
// Entry = (other_idx(18b) | dest_local(12b)<<18, w=0.5/d).

#define BLOCK 1024
#define NSLICES 10
#define CT_BLOCK 256
#define SC_BLOCK 256
#define SC_PPT 8
#define CA_BITS 12        // chunk = 4096 atoms
#define NCHUNK 49
#define FB_NSL 10
#define FB_UNROLL 8

__device__ __forceinline__ void fadd(float* p, float v) {
#if defined(__HIP_DEVICE_COMPILE__)
    unsafeAtomicAdd(p, v);   // native ds_add_f32 / global_atomic_add_f32
#else
    atomicAdd(p, v);
#endif
}

// ---------------- Pass 0: count entries per bucket (replicated hist) --------
__global__ __launch_bounds__(CT_BLOCK) void bucket_count(
    const int4* __restrict__ idx2, unsigned* __restrict__ counts, int npairs)
{
    __shared__ unsigned hist[NCHUNK * 4];
    for (int b = threadIdx.x; b < NCHUNK * 4; b += CT_BLOCK) hist[b] = 0;
    __syncthreads();
    const int n4 = npairs >> 1;                  // int4 = 2 pairs
    const int r = threadIdx.x & 3;
    const int stride = gridDim.x * CT_BLOCK;
    for (int q = blockIdx.x * CT_BLOCK + threadIdx.x; q < n4; q += stride) {
        int4 v = idx2[q];
        atomicAdd(&hist[(((unsigned)v.x >> CA_BITS) << 2) + r], 1u);
        atomicAdd(&hist[(((unsigned)v.y >> CA_BITS) << 2) + r], 1u);
        atomicAdd(&hist[(((unsigned)v.z >> CA_BITS) << 2) + r], 1u);
        atomicAdd(&hist[(((unsigned)v.w >> CA_BITS) << 2) + r], 1u);
    }
    // odd tail pair (npairs odd): one thread globally
    if ((npairs & 1) && blockIdx.x == 0 && threadIdx.x == 0) {
        const int2* idx = (const int2*)idx2;
        int2 ij = idx[npairs - 1];
        atomicAdd(&counts[(unsigned)ij.x >> CA_BITS], 1u);
        atomicAdd(&counts[(unsigned)ij.y >> CA_BITS], 1u);
    }
    __syncthreads();
    for (int b = threadIdx.x; b < NCHUNK; b += CT_BLOCK) {
        unsigned t = hist[4 * b] + hist[4 * b + 1] + hist[4 * b + 2] + hist[4 * b + 3];
        if (t) atomicAdd(&counts[b], t);
    }
}

// ---------------- prefix sum (49 elements) ----------------
__global__ void bucket_prefix(const unsigned* __restrict__ counts,
                              unsigned* __restrict__ offsets,
                              unsigned* __restrict__ cursors, int nbuckets)
{
    if (threadIdx.x == 0 && blockIdx.x == 0) {
        unsigned acc = 0;
        for (int b = 0; b < nbuckets; ++b) {
            offsets[b] = acc; cursors[b] = acc; acc += counts[b];
        }
        offsets[nbuckets] = acc;
    }
}

// ---------------- Pass A: scatter entries (replicated hist, exact ranks) ----
__global__ __launch_bounds__(SC_BLOCK) void bucket_scatter(
    const int2*  __restrict__ idx, const float* __restrict__ dist,
    uint2* __restrict__ entries, unsigned* __restrict__ cursors, int npairs)
{
    __shared__ unsigned hist[NCHUNK * 4];
    __shared__ unsigned rbase[NCHUNK * 4];
    for (int b = threadIdx.x; b < NCHUNK * 4; b += SC_BLOCK) hist[b] = 0;
    __syncthreads();

    const int p0 = blockIdx.x * (SC_BLOCK * SC_PPT) + threadIdx.x;
    const unsigned r = threadIdx.x & 3;
    unsigned key[2 * SC_PPT];
    unsigned brk[2 * SC_PPT];       // slot(8b: b*4+r) | rank<<8
    float    wv[SC_PPT];

#pragma unroll
    for (int k = 0; k < SC_PPT; ++k) {
        int p = p0 + k * SC_BLOCK;
        if (p < npairs) {
            int2 ij = idx[p];
            wv[k] = 0.5f / dist[p];
            unsigned s0 = (((unsigned)ij.x >> CA_BITS) << 2) + r;
            unsigned s1 = (((unsigned)ij.y >> CA_BITS) << 2) + r;
            key[2 * k]     = (unsigned)ij.y | (((unsigned)ij.x & ((1u << CA_BITS) - 1)) << 18);
            brk[2 * k]     = s0 | (atomicAdd(&hist[s0], 1u) << 8);
            key[2 * k + 1] = (unsigned)ij.x | (((unsigned)ij.y & ((1u << CA_BITS) - 1)) << 18);
            brk[2 * k + 1] = s1 | (atomicAdd(&hist[s1], 1u) << 8);
        } else {
            brk[2 * k] = brk[2 * k + 1] = 0xFFFFFFFFu;
        }
    }
    __syncthreads();
    if (threadIdx.x < NCHUNK) {
        int b = threadIdx.x;
        unsigned h0 = hist[4 * b], h1 = hist[4 * b + 1], h2 = hist[4 * b + 2], h3 = hist[4 * b + 3];
        unsigned tot = h0 + h1 + h2 + h3;
        unsigned g = tot ? atomicAdd(&cursors[b], tot) : 0u;
        rbase[4 * b]     = g;
        rbase[4 * b + 1] = g + h0;
        rbase[4 * b + 2] = g + h0 + h1;
        rbase[4 * b + 3] = g + h0 + h1 + h2;
    }
    __syncthreads();

#pragma unroll
    for (int k = 0; k < SC_PPT; ++k) {
        if (brk[2 * k] != 0xFFFFFFFFu) {
            unsigned wb = __float_as_uint(wv[k]);
            entries[rbase[brk[2 * k] & 255u] + (brk[2 * k] >> 8)] =
                make_uint2(key[2 * k], wb);
            entries[rbase[brk[2 * k + 1] & 255u] + (brk[2 * k + 1] >> 8)] =
                make_uint2(key[2 * k + 1], wb);
        }
    }
}

// ---------------- Pass B: chunk scan, channel-major LDS slab ----------------
template<int CHUNK_ATOMS>
__global__ __launch_bounds__(BLOCK) void bucket_scan(
    const float4* __restrict__ charges, const uint2* __restrict__ entries,
    const unsigned* __restrict__ offsets, float* __restrict__ slabs,
    int natoms)
{
    constexpr int CH_ELEMS = CHUNK_ATOMS * 4;
    extern __shared__ float sm[];   // layout: [4][CHUNK_ATOMS] channel-major

    const int c  = blockIdx.x / NSLICES;
    const int s  = blockIdx.x - c * NSLICES;
    for (int e = threadIdx.x; e < CH_ELEMS; e += BLOCK) sm[e] = 0.f;
    __syncthreads();

    const unsigned beg = offsets[c];
    const unsigned cnt = offsets[c + 1] - beg;
    const unsigned e0  = beg + (unsigned)((unsigned long long)cnt * s       / NSLICES);
    const unsigned e1  = beg + (unsigned)((unsigned long long)cnt * (s + 1) / NSLICES);

    auto process = [&](uint2 en) {
        float4 cq = charges[en.x & 0x3FFFFu];
        float w = __uint_as_float(en.y);
        unsigned d = en.x >> 18;
        fadd(sm + 0 * CHUNK_ATOMS + d, cq.x * w);
        fadd(sm + 1 * CHUNK_ATOMS + d, cq.y * w);
        fadd(sm + 2 * CHUNK_ATOMS + d, cq.z * w);
        fadd(sm + 3 * CHUNK_ATOMS + d, cq.w * w);
    };

    // head: align entry index to even for uint4 loads
    const unsigned e0a = min(e1, (e0 + 1u) & ~1u);
    for (unsigned e = e0 + threadIdx.x; e < e0a; e += BLOCK) process(entries[e]);

    const uint4* ent4 = (const uint4*)entries;
    const unsigned base = e0a >> 1;            // uint4 index
    const unsigned n4   = (e1 - e0a) >> 1;     // number of uint4s (each = 2 entries)
    const unsigned nb   = n4 / (BLOCK * 4);    // 8 entries per thread per batch

    unsigned q = base + threadIdx.x;
    for (unsigned b = 0; b < nb; ++b, q += BLOCK * 4) {
        uint4 E[4];
#pragma unroll
        for (int u = 0; u < 4; ++u) E[u] = ent4[q + u * BLOCK];
        float4 cq[8];
#pragma unroll
        for (int u = 0; u < 4; ++u) {
            cq[2 * u]     = charges[E[u].x & 0x3FFFFu];
            cq[2 * u + 1] = charges[E[u].z & 0x3FFFFu];
        }
#pragma unroll
        for (int u = 0; u < 4; ++u) {
            float w0 = __uint_as_float(E[u].y);
            unsigned d0 = E[u].x >> 18;
            fadd(sm + 0 * CHUNK_ATOMS + d0, cq[2 * u].x * w0);
            fadd(sm + 1 * CHUNK_ATOMS + d0, cq[2 * u].y * w0);
            fadd(sm + 2 * CHUNK_ATOMS + d0, cq[2 * u].z * w0);
            fadd(sm + 3 * CHUNK_ATOMS + d0, cq[2 * u].w * w0);
            float w1 = __uint_as_float(E[u].w);
            unsigned d1 = E[u].z >> 18;
            fadd(sm + 0 * CHUNK_ATOMS + d1, cq[2 * u + 1].x * w1);
            fadd(sm + 1 * CHUNK_ATOMS + d1, cq[2 * u + 1].y * w1);
            fadd(sm + 2 * CHUNK_ATOMS + d1, cq[2 * u + 1].z * w1);
            fadd(sm + 3 * CHUNK_ATOMS + d1, cq[2 * u + 1].w * w1);
        }
    }
    // uint4 tail
    for (unsigned q2 = base + nb * (BLOCK * 4) + threadIdx.x; q2 < base + n4; q2 += BLOCK) {
        uint4 E = ent4[q2];
        process(make_uint2(E.x, E.y));
        process(make_uint2(E.z, E.w));
    }
    // odd final entry
    for (unsigned e = e0a + 2 * n4 + threadIdx.x; e < e1; e += BLOCK) process(entries[e]);
    __syncthreads();

    // writeout: global slab stays atom-major (atom*4+ch); read LDS transposed
    const int c0 = c * CHUNK_ATOMS;
    const int nvalid = min(CHUNK_ATOMS, natoms - c0) * 4;
    float* dst = slabs + (size_t)blockIdx.x * CH_ELEMS;
    for (int e2 = threadIdx.x; e2 < nvalid; e2 += BLOCK)
        dst[e2] = sm[(e2 & 3) * CHUNK_ATOMS + (e2 >> 2)];
    (void)natoms;
}

// ---------------- slab reduce (float4) ----------------
template<int CH_ELEMS, int NS>
__global__ __launch_bounds__(256) void chunk_reduce(
    const float4* __restrict__ ws, float4* __restrict__ out, int total4)
{
    int g = blockIdx.x * blockDim.x + threadIdx.x;
    if (g >= total4) return;
    constexpr int CH4 = CH_ELEMS / 4;
    int c = g / CH4;
    int local = g - c * CH4;
    const float4* p = ws + ((size_t)c * NS) * CH4 + local;
    float4 acc = make_float4(0.f, 0.f, 0.f, 0.f);
#pragma unroll
    for (int s = 0; s < NS; ++s) {
        float4 v = p[(size_t)s * CH4];
        acc.x += v.x; acc.y += v.y; acc.z += v.z; acc.w += v.w;
    }
    out[g] = acc;
}

// ---------------- Fallback (R3): redundant chunk scan ----------------
template<int CHUNK_ATOMS, bool USE_WS>
__global__ __launch_bounds__(BLOCK) void chunk_scan(
    const float4* __restrict__ charges, const int2* __restrict__ idx,
    const float* __restrict__ dist, float* __restrict__ dest,
    int npairs, int natoms)
{
    constexpr int CH_ELEMS = CHUNK_ATOMS * 4;
    extern __shared__ float sm[];
    const int c  = blockIdx.x / FB_NSL;
    const int s  = blockIdx.x - c * FB_NSL;
    const int c0 = c * CHUNK_ATOMS;
    const int cn = min(CHUNK_ATOMS, natoms - c0);
    for (int e = threadIdx.x; e < CH_ELEMS; e += BLOCK) sm[e] = 0.f;
    __syncthreads();
    const int p0 = (int)((long long)npairs * s       / FB_NSL);
    const int p1 = (int)((long long)npairs * (s + 1) / FB_NSL);
    const int nbatch = (p1 - p0) / (BLOCK * FB_UNROLL);
    int p = p0 + threadIdx.x;
    for (int b = 0; b < nbatch; ++b, p += BLOCK * FB_UNROLL) {
        int2 ij[FB_UNROLL]; float dd[FB_UNROLL];
#pragma unroll
        for (int u = 0; u < FB_UNROLL; ++u) { ij[u] = idx[p + u * BLOCK]; dd[u] = dist[p + u * BLOCK]; }
#pragma unroll
        for (int u = 0; u < FB_UNROLL; ++u) {
            unsigned li = (unsigned)(ij[u].x - c0), lj = (unsigned)(ij[u].y - c0);
            float w = 0.5f / dd[u];
            if (li < (unsigned)cn) {
                float4 cq = charges[ij[u].y]; float* bp = sm + li * 4;
                fadd(bp + 0, cq.x * w); fadd(bp + 1, cq.y * w);
                fadd(bp + 2, cq.z * w); fadd(bp + 3, cq.w * w);
            }
            if (lj < (unsigned)cn) {
                float4 cq = charges[ij[u].x]; float* bp = sm + lj * 4;
                fadd(bp + 0, cq.x * w); fadd(bp + 1, cq.y * w);
                fadd(bp + 2, cq.z * w); fadd(bp + 3, cq.w * w);
            }
        }
    }
    for (; p < p1; p += BLOCK) {
        int2 ij = idx[p];
        unsigned li = (unsigned)(ij.x - c0), lj = (unsigned)(ij.y - c0);
        if (li < (unsigned)cn || lj < (unsigned)cn) {
            float w = 0.5f / dist[p];
            if (li < (unsigned)cn) {
                float4 cq = charges[ij.y]; float* bp = sm + li * 4;
                fadd(bp + 0, cq.x * w); fadd(bp + 1, cq.y * w);
                fadd(bp + 2, cq.z * w); fadd(bp + 3, cq.w * w);
            }
            if (lj < (unsigned)cn) {
                float4 cq = charges[ij.x]; float* bp = sm + lj * 4;
                fadd(bp + 0, cq.x * w); fadd(bp + 1, cq.y * w);
                fadd(bp + 2, cq.z * w); fadd(bp + 3, cq.w * w);
            }
        }
    }
    __syncthreads();
    const int nvalid = cn * 4;
    if (USE_WS) {
        float* dst = dest + (size_t)blockIdx.x * CH_ELEMS;
        for (int e = threadIdx.x; e < nvalid; e += BLOCK) dst[e] = sm[e];
    } else {
        float* dst = dest + (size_t)c0 * 4;
        for (int e = threadIdx.x; e < nvalid; e += BLOCK) fadd(dst + e, sm[e]);
    }
}

extern "C" void kernel_launch(void* const* d_in, const int* in_sizes, int n_in,
                              void* d_out, int out_size, void* d_ws, size_t ws_size,
                              hipStream_t stream) {
    const float4* charges = (const float4*)d_in[0];
    const int2*   idx     = (const int2*)  d_in[1];
    const float*  dist    = (const float*) d_in[2];
    float*        out     = (float*)d_out;

    const int natoms = in_sizes[0] / 4;     // 200000
    const int npairs = in_sizes[2];         // 8000000
    const int total  = out_size;            // 800000

    int dev = 0;
    hipGetDevice(&dev);
    int maxShm = 0;
    hipDeviceGetAttribute(&maxShm, hipDeviceAttributeMaxSharedMemoryPerBlock, dev);
    const bool big = (maxShm >= 65536);

    constexpr int CA = 4096, CE = CA * 4;          // 64 KiB slab -> 2 blocks/CU
    const int C    = (natoms + CA - 1) / CA;       // 49
    const int grid = C * NSLICES;                  // 490

    const size_t ENT_OFF    = 1024;
    const size_t ent_bytes  = (size_t)2 * npairs * sizeof(uint2);  // 128 MB
    size_t slab_off         = (ENT_OFF + ent_bytes + 255) & ~(size_t)255;
    const size_t slab_bytes = (size_t)grid * CE * sizeof(float);   // 32.1 MB
    const size_t need       = slab_off + slab_bytes;

    if (big && ws_size >= need && natoms <= (1 << 18) && C == NCHUNK && (total & 3) == 0) {
        unsigned* counts  = (unsigned*)d_ws;               // [49]
        unsigned* offsets = (unsigned*)((char*)d_ws + 256);// [50]
        unsigned* cursors = (unsigned*)((char*)d_ws + 512);// [49]
        uint2*    entries = (uint2*)((char*)d_ws + ENT_OFF);
        float*    slabs   = (float*)((char*)d_ws + slab_off);

        hipMemsetAsync(d_ws, 0, 1024, stream);
        bucket_count<<<1024, CT_BLOCK, 0, stream>>>((const int4*)idx, counts, npairs);
        bucket_prefix<<<1, 32, 0, stream>>>(counts, offsets, cursors, C);
        const int sc_grid = (npairs + SC_BLOCK * SC_PPT - 1) / (SC_BLOCK * SC_PPT);
        bucket_scatter<<<sc_grid, SC_BLOCK, 0, stream>>>(idx, dist, entries, cursors, npairs);
        hipFuncSetAttribute((const void*)bucket_scan<CA>,
                            hipFuncAttributeMaxDynamicSharedMemorySize, CE * 4);
        bucket_scan<CA><<<grid, BLOCK, CE * 4, stream>>>(charges, entries, offsets, slabs, natoms);
        chunk_reduce<CE, NSLICES><<<(total / 4 + 255) / 256, 256, 0, stream>>>(
            (const float4*)slabs, (float4*)out, total / 4);
    } else if (big) {
        const size_t ws_need = (size_t)grid * CE * sizeof(float);
        if (ws_size >= ws_need && (total & 3) == 0) {
            hipFuncSetAttribute((const void*)chunk_scan<CA, true>,
                                hipFuncAttributeMaxDynamicSharedMemorySize, CE * 4);
            chunk_scan<CA, true><<<grid, BLOCK, CE * 4, stream>>>(
                charges, idx, dist, (float*)d_ws, npairs, natoms);
            chunk_reduce<CE, FB_NSL><<<(total / 4 + 255) / 256, 256, 0, stream>>>(
                (const float4*)d_ws, (float4*)out, total / 4);
        } else {
            hipMemsetAsync(d_out, 0, (size_t)total * sizeof(float), stream);
            hipFuncSetAttribute((const void*)chunk_scan<CA, false>,
                                hipFuncAttributeMaxDynamicSharedMemorySize, CE * 4);
            chunk_scan<CA, false><<<grid, BLOCK, CE * 4, stream>>>(
                charges, idx, dist, out, npairs, natoms);
        }
    } else {
        constexpr int CA2 = 2048, CE2 = CA2 * 4;
        const int C2 = (natoms + CA2 - 1) / CA2;
        const int grid2 = C2 * FB_NSL;
        const size_t ws_need = (size_t)grid2 * CE2 * sizeof(float);
        if (ws_size >= ws_need && (total & 3) == 0) {
            chunk_scan<CA2, true><<<grid2, BLOCK, CE2 * 4, stream>>>(
                charges, idx, dist, (float*)d_ws, npairs, natoms);
            chunk_reduce<CE2, FB_NSL><<<(total / 4 + 255) / 256, 256, 0, stream>>>(
                (const float4*)d_ws, (float4*)out, total / 4);
        } else {
            hipMemsetAsync(d_out, 0, (size_t)total * sizeof(float), stream);
            chunk_scan<CA2, false><<<grid2, BLOCK, CE2 * 4, stream>>>(
                charges, idx, dist, out, npairs, natoms);
        }
    }
}

// Round 5
// 436.248 us; speedup vs baseline: 1.3935x; 1.3935x over previous
//
#include <hip/hip_runtime.h>
#include <hip/hip_fp16.h>

// Round 12: packed-f16 LDS accumulation, take 2 (inline-asm ds_pk_add_f16).
//   R11 never ran -- container failure is most consistent with a COMPILE
//   error: unsafeAtomicAdd has no __half2 overload in HIP headers. Fix:
//   pkadd is now inline asm "ds_pk_add_f16 vaddr, vdata" (CDNA native,
//   gfx90a+), LDS offset = low 32 bits of the generic pointer, data as
//   32-bit reg. No header dependence, no CAS ambiguity.
//   Design rationale (R8-R10 elimination): occupancy/bank-layout/lowering
//   all invariant at 349us -> LDS fp-atomic pipe floor ~3.3 cyc/lane-op;
//   64M lane-atomics = 344us. Halve the op count: 4 channels as two
//   __half2 planes -> 2 ds_pk_add_f16 per entry. Planes padded +16
//   half2 so an entry's two atomics hit banks d%32 and (d+16)%32.
//   Precision: ~8 f16 adds per cell per slice (NSLICES=10), f32
//   cross-slice reduce; predicted absmax ~0.02-0.04 (0.031 passed in R7).
// Entry = (other_idx(18b) | dest_local(12b)<<18, w=0.5/d).

#define BLOCK 1024
#define NSLICES 10
#define CT_BLOCK 256
#define SC_BLOCK 256
#define SC_PPT 8
#define CA_BITS 12        // chunk = 4096 atoms
#define NCHUNK 49
#define PLANE_PAD 16      // half2s; 4112 % 32 == 16 -> plane1 bank offset +16
#define FB_NSL 10
#define FB_UNROLL 8

__device__ __forceinline__ void fadd(float* p, float v) {
#if defined(__HIP_DEVICE_COMPILE__)
    unsafeAtomicAdd(p, v);
#else
    atomicAdd(p, v);
#endif
}

// Native packed-f16 LDS atomic add, no return. The DS instruction takes the
// 32-bit LDS byte offset; for a generic pointer into __shared__, that is the
// low 32 bits. Data passed as 32-bit register (2 x f16).
__device__ __forceinline__ void pkadd(__half2* p, float lo, float hi) {
#if defined(__HIP_DEVICE_COMPILE__)
    __half2 v = __float22half2_rn(make_float2(lo, hi));
    unsigned bits;
    __builtin_memcpy(&bits, &v, 4);
    unsigned off = (unsigned)(unsigned long long)(void*)p;
    asm volatile("ds_pk_add_f16 %0, %1" :: "v"(off), "v"(bits) : "memory");
#else
    (void)p; (void)lo; (void)hi;
#endif
}

// ---------------- Pass 0: count entries per bucket (replicated hist) --------
__global__ __launch_bounds__(CT_BLOCK) void bucket_count(
    const int4* __restrict__ idx2, unsigned* __restrict__ counts, int npairs)
{
    __shared__ unsigned hist[NCHUNK * 4];
    for (int b = threadIdx.x; b < NCHUNK * 4; b += CT_BLOCK) hist[b] = 0;
    __syncthreads();
    const int n4 = npairs >> 1;                  // int4 = 2 pairs
    const int r = threadIdx.x & 3;
    const int stride = gridDim.x * CT_BLOCK;
    for (int q = blockIdx.x * CT_BLOCK + threadIdx.x; q < n4; q += stride) {
        int4 v = idx2[q];
        atomicAdd(&hist[(((unsigned)v.x >> CA_BITS) << 2) + r], 1u);
        atomicAdd(&hist[(((unsigned)v.y >> CA_BITS) << 2) + r], 1u);
        atomicAdd(&hist[(((unsigned)v.z >> CA_BITS) << 2) + r], 1u);
        atomicAdd(&hist[(((unsigned)v.w >> CA_BITS) << 2) + r], 1u);
    }
    // odd tail pair (npairs odd): one thread globally
    if ((npairs & 1) && blockIdx.x == 0 && threadIdx.x == 0) {
        const int2* idx = (const int2*)idx2;
        int2 ij = idx[npairs - 1];
        atomicAdd(&counts[(unsigned)ij.x >> CA_BITS], 1u);
        atomicAdd(&counts[(unsigned)ij.y >> CA_BITS], 1u);
    }
    __syncthreads();
    for (int b = threadIdx.x; b < NCHUNK; b += CT_BLOCK) {
        unsigned t = hist[4 * b] + hist[4 * b + 1] + hist[4 * b + 2] + hist[4 * b + 3];
        if (t) atomicAdd(&counts[b], t);
    }
}

// ---------------- prefix sum (49 elements) ----------------
__global__ void bucket_prefix(const unsigned* __restrict__ counts,
                              unsigned* __restrict__ offsets,
                              unsigned* __restrict__ cursors, int nbuckets)
{
    if (threadIdx.x == 0 && blockIdx.x == 0) {
        unsigned acc = 0;
        for (int b = 0; b < nbuckets; ++b) {
            offsets[b] = acc; cursors[b] = acc; acc += counts[b];
        }
        offsets[nbuckets] = acc;
    }
}

// ---------------- Pass A: scatter entries (replicated hist, exact ranks) ----
__global__ __launch_bounds__(SC_BLOCK) void bucket_scatter(
    const int2*  __restrict__ idx, const float* __restrict__ dist,
    uint2* __restrict__ entries, unsigned* __restrict__ cursors, int npairs)
{
    __shared__ unsigned hist[NCHUNK * 4];
    __shared__ unsigned rbase[NCHUNK * 4];
    for (int b = threadIdx.x; b < NCHUNK * 4; b += SC_BLOCK) hist[b] = 0;
    __syncthreads();

    const int p0 = blockIdx.x * (SC_BLOCK * SC_PPT) + threadIdx.x;
    const unsigned r = threadIdx.x & 3;
    unsigned key[2 * SC_PPT];
    unsigned brk[2 * SC_PPT];       // slot(8b: b*4+r) | rank<<8
    float    wv[SC_PPT];

#pragma unroll
    for (int k = 0; k < SC_PPT; ++k) {
        int p = p0 + k * SC_BLOCK;
        if (p < npairs) {
            int2 ij = idx[p];
            wv[k] = 0.5f / dist[p];
            unsigned s0 = (((unsigned)ij.x >> CA_BITS) << 2) + r;
            unsigned s1 = (((unsigned)ij.y >> CA_BITS) << 2) + r;
            key[2 * k]     = (unsigned)ij.y | (((unsigned)ij.x & ((1u << CA_BITS) - 1)) << 18);
            brk[2 * k]     = s0 | (atomicAdd(&hist[s0], 1u) << 8);
            key[2 * k + 1] = (unsigned)ij.x | (((unsigned)ij.y & ((1u << CA_BITS) - 1)) << 18);
            brk[2 * k + 1] = s1 | (atomicAdd(&hist[s1], 1u) << 8);
        } else {
            brk[2 * k] = brk[2 * k + 1] = 0xFFFFFFFFu;
        }
    }
    __syncthreads();
    if (threadIdx.x < NCHUNK) {
        int b = threadIdx.x;
        unsigned h0 = hist[4 * b], h1 = hist[4 * b + 1], h2 = hist[4 * b + 2], h3 = hist[4 * b + 3];
        unsigned tot = h0 + h1 + h2 + h3;
        unsigned g = tot ? atomicAdd(&cursors[b], tot) : 0u;
        rbase[4 * b]     = g;
        rbase[4 * b + 1] = g + h0;
        rbase[4 * b + 2] = g + h0 + h1;
        rbase[4 * b + 3] = g + h0 + h1 + h2;
    }
    __syncthreads();

#pragma unroll
    for (int k = 0; k < SC_PPT; ++k) {
        if (brk[2 * k] != 0xFFFFFFFFu) {
            unsigned wb = __float_as_uint(wv[k]);
            entries[rbase[brk[2 * k] & 255u] + (brk[2 * k] >> 8)] =
                make_uint2(key[2 * k], wb);
            entries[rbase[brk[2 * k + 1] & 255u] + (brk[2 * k + 1] >> 8)] =
                make_uint2(key[2 * k + 1], wb);
        }
    }
}

// ---------------- Pass B: chunk scan, packed-f16 LDS accumulation ----------
template<int CHUNK_ATOMS>
__global__ __launch_bounds__(BLOCK) void bucket_scan(
    const float4* __restrict__ charges, const uint2* __restrict__ entries,
    const unsigned* __restrict__ offsets, float* __restrict__ slabs,
    int natoms)
{
    constexpr int PLANE = CHUNK_ATOMS + PLANE_PAD;   // half2s per plane
    extern __shared__ __half2 sm2[];                 // [2][PLANE]
    __half2* smp0 = sm2;                             // ch0,ch1
    __half2* smp1 = sm2 + PLANE;                     // ch2,ch3

    const int c  = blockIdx.x / NSLICES;
    const int s  = blockIdx.x - c * NSLICES;
    {
        unsigned* z = (unsigned*)sm2;
        for (int e = threadIdx.x; e < 2 * PLANE; e += BLOCK) z[e] = 0u;
    }
    __syncthreads();

    const unsigned beg = offsets[c];
    const unsigned cnt = offsets[c + 1] - beg;
    const unsigned e0  = beg + (unsigned)((unsigned long long)cnt * s       / NSLICES);
    const unsigned e1  = beg + (unsigned)((unsigned long long)cnt * (s + 1) / NSLICES);

    auto process = [&](uint2 en) {
        float4 cq = charges[en.x & 0x3FFFFu];
        float w = __uint_as_float(en.y);
        unsigned d = en.x >> 18;
        pkadd(smp0 + d, cq.x * w, cq.y * w);
        pkadd(smp1 + d, cq.z * w, cq.w * w);
    };

    // head: align entry index to even for uint4 loads
    const unsigned e0a = min(e1, (e0 + 1u) & ~1u);
    for (unsigned e = e0 + threadIdx.x; e < e0a; e += BLOCK) process(entries[e]);

    const uint4* ent4 = (const uint4*)entries;
    const unsigned base = e0a >> 1;            // uint4 index
    const unsigned n4   = (e1 - e0a) >> 1;     // number of uint4s (each = 2 entries)
    const unsigned nb   = n4 / (BLOCK * 4);    // 8 entries per thread per batch

    unsigned q = base + threadIdx.x;
    for (unsigned b = 0; b < nb; ++b, q += BLOCK * 4) {
        uint4 E[4];
#pragma unroll
        for (int u = 0; u < 4; ++u) E[u] = ent4[q + u * BLOCK];
        float4 cq[8];
#pragma unroll
        for (int u = 0; u < 4; ++u) {
            cq[2 * u]     = charges[E[u].x & 0x3FFFFu];
            cq[2 * u + 1] = charges[E[u].z & 0x3FFFFu];
        }
#pragma unroll
        for (int u = 0; u < 4; ++u) {
            float w0 = __uint_as_float(E[u].y);
            unsigned d0 = E[u].x >> 18;
            pkadd(smp0 + d0, cq[2 * u].x * w0, cq[2 * u].y * w0);
            pkadd(smp1 + d0, cq[2 * u].z * w0, cq[2 * u].w * w0);
            float w1 = __uint_as_float(E[u].w);
            unsigned d1 = E[u].z >> 18;
            pkadd(smp0 + d1, cq[2 * u + 1].x * w1, cq[2 * u + 1].y * w1);
            pkadd(smp1 + d1, cq[2 * u + 1].z * w1, cq[2 * u + 1].w * w1);
        }
    }
    // uint4 tail
    for (unsigned q2 = base + nb * (BLOCK * 4) + threadIdx.x; q2 < base + n4; q2 += BLOCK) {
        uint4 E = ent4[q2];
        process(make_uint2(E.x, E.y));
        process(make_uint2(E.z, E.w));
    }
    // odd final entry
    for (unsigned e = e0a + 2 * n4 + threadIdx.x; e < e1; e += BLOCK) process(entries[e]);
    __syncthreads();

    // writeout: global slab stays f32 atom-major (atom*4+ch)
    const int c0 = c * CHUNK_ATOMS;
    const int cn = min(CHUNK_ATOMS, natoms - c0);
    float4* dst = (float4*)(slabs + (size_t)blockIdx.x * (CHUNK_ATOMS * 4));
    for (int a = threadIdx.x; a < cn; a += BLOCK) {
        float2 f01 = __half22float2(smp0[a]);
        float2 f23 = __half22float2(smp1[a]);
        dst[a] = make_float4(f01.x, f01.y, f23.x, f23.y);
    }
}

// ---------------- slab reduce (float4) ----------------
template<int CH_ELEMS, int NS>
__global__ __launch_bounds__(256) void chunk_reduce(
    const float4* __restrict__ ws, float4* __restrict__ out, int total4)
{
    int g = blockIdx.x * blockDim.x + threadIdx.x;
    if (g >= total4) return;
    constexpr int CH4 = CH_ELEMS / 4;
    int c = g / CH4;
    int local = g - c * CH4;
    const float4* p = ws + ((size_t)c * NS) * CH4 + local;
    float4 acc = make_float4(0.f, 0.f, 0.f, 0.f);
#pragma unroll
    for (int s = 0; s < NS; ++s) {
        float4 v = p[(size_t)s * CH4];
        acc.x += v.x; acc.y += v.y; acc.z += v.z; acc.w += v.w;
    }
    out[g] = acc;
}

// ---------------- Fallback (R3): redundant chunk scan ----------------
template<int CHUNK_ATOMS, bool USE_WS>
__global__ __launch_bounds__(BLOCK) void chunk_scan(
    const float4* __restrict__ charges, const int2* __restrict__ idx,
    const float* __restrict__ dist, float* __restrict__ dest,
    int npairs, int natoms)
{
    constexpr int CH_ELEMS = CHUNK_ATOMS * 4;
    extern __shared__ float sm[];
    const int c  = blockIdx.x / FB_NSL;
    const int s  = blockIdx.x - c * FB_NSL;
    const int c0 = c * CHUNK_ATOMS;
    const int cn = min(CHUNK_ATOMS, natoms - c0);
    for (int e = threadIdx.x; e < CH_ELEMS; e += BLOCK) sm[e] = 0.f;
    __syncthreads();
    const int p0 = (int)((long long)npairs * s       / FB_NSL);
    const int p1 = (int)((long long)npairs * (s + 1) / FB_NSL);
    const int nbatch = (p1 - p0) / (BLOCK * FB_UNROLL);
    int p = p0 + threadIdx.x;
    for (int b = 0; b < nbatch; ++b, p += BLOCK * FB_UNROLL) {
        int2 ij[FB_UNROLL]; float dd[FB_UNROLL];
#pragma unroll
        for (int u = 0; u < FB_UNROLL; ++u) { ij[u] = idx[p + u * BLOCK]; dd[u] = dist[p + u * BLOCK]; }
#pragma unroll
        for (int u = 0; u < FB_UNROLL; ++u) {
            unsigned li = (unsigned)(ij[u].x - c0), lj = (unsigned)(ij[u].y - c0);
            float w = 0.5f / dd[u];
            if (li < (unsigned)cn) {
                float4 cq = charges[ij[u].y]; float* bp = sm + li * 4;
                fadd(bp + 0, cq.x * w); fadd(bp + 1, cq.y * w);
                fadd(bp + 2, cq.z * w); fadd(bp + 3, cq.w * w);
            }
            if (lj < (unsigned)cn) {
                float4 cq = charges[ij[u].x]; float* bp = sm + lj * 4;
                fadd(bp + 0, cq.x * w); fadd(bp + 1, cq.y * w);
                fadd(bp + 2, cq.z * w); fadd(bp + 3, cq.w * w);
            }
        }
    }
    for (; p < p1; p += BLOCK) {
        int2 ij = idx[p];
        unsigned li = (unsigned)(ij.x - c0), lj = (unsigned)(ij.y - c0);
        if (li < (unsigned)cn || lj < (unsigned)cn) {
            float w = 0.5f / dist[p];
            if (li < (unsigned)cn) {
                float4 cq = charges[ij.y]; float* bp = sm + li * 4;
                fadd(bp + 0, cq.x * w); fadd(bp + 1, cq.y * w);
                fadd(bp + 2, cq.z * w); fadd(bp + 3, cq.w * w);
            }
            if (lj < (unsigned)cn) {
                float4 cq = charges[ij.x]; float* bp = sm + lj * 4;
                fadd(bp + 0, cq.x * w); fadd(bp + 1, cq.y * w);
                fadd(bp + 2, cq.z * w); fadd(bp + 3, cq.w * w);
            }
        }
    }
    __syncthreads();
    const int nvalid = cn * 4;
    if (USE_WS) {
        float* dst = dest + (size_t)blockIdx.x * CH_ELEMS;
        for (int e = threadIdx.x; e < nvalid; e += BLOCK) dst[e] = sm[e];
    } else {
        float* dst = dest + (size_t)c0 * 4;
        for (int e = threadIdx.x; e < nvalid; e += BLOCK) fadd(dst + e, sm[e]);
    }
}

extern "C" void kernel_launch(void* const* d_in, const int* in_sizes, int n_in,
                              void* d_out, int out_size, void* d_ws, size_t ws_size,
                              hipStream_t stream) {
    const float4* charges = (const float4*)d_in[0];
    const int2*   idx     = (const int2*)  d_in[1];
    const float*  dist    = (const float*) d_in[2];
    float*        out     = (float*)d_out;

    const int natoms = in_sizes[0] / 4;     // 200000
    const int npairs = in_sizes[2];         // 8000000
    const int total  = out_size;            // 800000

    int dev = 0;
    hipGetDevice(&dev);
    int maxShm = 0;
    hipDeviceGetAttribute(&maxShm, hipDeviceAttributeMaxSharedMemoryPerBlock, dev);
    const bool big = (maxShm >= 65536);

    constexpr int CA = 4096, CE = CA * 4;
    const int C    = (natoms + CA - 1) / CA;       // 49
    const int grid = C * NSLICES;                  // 490
    const size_t scan_shm = (size_t)2 * (CA + PLANE_PAD) * sizeof(__half2); // ~33 KB

    const size_t ENT_OFF    = 1024;
    const size_t ent_bytes  = (size_t)2 * npairs * sizeof(uint2);  // 128 MB
    size_t slab_off         = (ENT_OFF + ent_bytes + 255) & ~(size_t)255;
    const size_t slab_bytes = (size_t)grid * CE * sizeof(float);   // 32.1 MB
    const size_t need       = slab_off + slab_bytes;

    if (big && ws_size >= need && natoms <= (1 << 18) && C == NCHUNK && (total & 3) == 0) {
        unsigned* counts  = (unsigned*)d_ws;               // [49]
        unsigned* offsets = (unsigned*)((char*)d_ws + 256);// [50]
        unsigned* cursors = (unsigned*)((char*)d_ws + 512);// [49]
        uint2*    entries = (uint2*)((char*)d_ws + ENT_OFF);
        float*    slabs   = (float*)((char*)d_ws + slab_off);

        hipMemsetAsync(d_ws, 0, 1024, stream);
        bucket_count<<<1024, CT_BLOCK, 0, stream>>>((const int4*)idx, counts, npairs);
        bucket_prefix<<<1, 32, 0, stream>>>(counts, offsets, cursors, C);
        const int sc_grid = (npairs + SC_BLOCK * SC_PPT - 1) / (SC_BLOCK * SC_PPT);
        bucket_scatter<<<sc_grid, SC_BLOCK, 0, stream>>>(idx, dist, entries, cursors, npairs);
        hipFuncSetAttribute((const void*)bucket_scan<CA>,
                            hipFuncAttributeMaxDynamicSharedMemorySize, (int)scan_shm);
        bucket_scan<CA><<<grid, BLOCK, scan_shm, stream>>>(charges, entries, offsets, slabs, natoms);
        chunk_reduce<CE, NSLICES><<<(total / 4 + 255) / 256, 256, 0, stream>>>(
            (const float4*)slabs, (float4*)out, total / 4);
    } else if (big) {
        const size_t ws_need = (size_t)grid * CE * sizeof(float);
        if (ws_size >= ws_need && (total & 3) == 0) {
            hipFuncSetAttribute((const void*)chunk_scan<CA, true>,
                                hipFuncAttributeMaxDynamicSharedMemorySize, CE * 4);
            chunk_scan<CA, true><<<grid, BLOCK, CE * 4, stream>>>(
                charges, idx, dist, (float*)d_ws, npairs, natoms);
            chunk_reduce<CE, FB_NSL><<<(total / 4 + 255) / 256, 256, 0, stream>>>(
                (const float4*)d_ws, (float4*)out, total / 4);
        } else {
            hipMemsetAsync(d_out, 0, (size_t)total * sizeof(float), stream);
            hipFuncSetAttribute((const void*)chunk_scan<CA, false>,
                                hipFuncAttributeMaxDynamicSharedMemorySize, CE * 4);
            chunk_scan<CA, false><<<grid, BLOCK, CE * 4, stream>>>(
                charges, idx, dist, out, npairs, natoms);
        }
    } else {
        constexpr int CA2 = 2048, CE2 = CA2 * 4;
        const int C2 = (natoms + CA2 - 1) / CA2;
        const int grid2 = C2 * FB_NSL;
        const size_t ws_need = (size_t)grid2 * CE2 * sizeof(float);
        if (ws_size >= ws_need && (total & 3) == 0) {
            chunk_scan<CA2, true><<<grid2, BLOCK, CE2 * 4, stream>>>(
                charges, idx, dist, (float*)d_ws, npairs, natoms);
            chunk_reduce<CE2, FB_NSL><<<(total / 4 + 255) / 256, 256, 0, stream>>>(
                (const float4*)d_ws, (float4*)out, total / 4);
        } else {
            hipMemsetAsync(d_out, 0, (size_t)total * sizeof(float), stream);
            chunk_scan<CA2, false><<<grid2, BLOCK, CE2 * 4, stream>>>(
                charges, idx, dist, out, npairs, natoms);
        }
    }
}